// Round 13
// baseline (24.883 us; speedup 1.0000x reference)
//
#include <hip/hip_runtime.h>

// Problem constants (fixed by setup_inputs): B=8, L=16384, H=2, BLOCK=128, VOCAB=32000
#define NB        8
#define LLEN      16384
#define NHEAD     2
#define BLOCKSZ   128
#define VOCAB     32000
#define NBLK      (LLEN / BLOCKSZ)                  // 128
#define NCHUNK    (NB * NBLK)                       // 1024
#define TOKS_PER_CHUNK (BLOCKSZ * NHEAD)            // 256
#define NT_COLS   (TOKS_PER_CHUNK + LLEN * NHEAD)   // 33024 per batch row
#define NT_TOTAL  (NB * NT_COLS)                    // 264192
#define CAT_TOTAL (NB * TOKS_PER_CHUNK)             // 2048
#define HIST_OFF  (NT_TOTAL + CAT_TOTAL)            // 266240
#define NF4       (VOCAB / 4)                       // 8000 f4 slots per row
#define NSPLIT    4
#define QF4       (NF4 / NSPLIT)                    // 2000 f4 slots per quarter
#define QTAIL     (QF4 - 3 * 512)                   // 464 tail f4s (threads t<464)
#define NTHR      512
#define CAP       8                                 // bucket capacity (overflow -> fallback)
#define CAPP      9                                 // padded stride

typedef float f32x4 __attribute__((ext_vector_type(4)));

// 4096 blocks x 512 threads: one per (chunk, quarter); XCD mapping chunk=bid&1023,
// q=bid>>10 keeps a chunk's 4 splits on one XCD. vs R12: same 4 dispatch rounds
// (wave-capped 4 blocks/CU) but HALF the prologues — each prologue amortized
// over 2x the stores. Final-value burst (every f4 written once, no drain/rewrite).
__global__ __launch_bounds__(NTHR) void fused_kernel(const int* __restrict__ tokens,
                                                     float* __restrict__ out) {
    __shared__ int toks[TOKS_PER_CHUNK];
    __shared__ unsigned bcnt[NTHR];
    __shared__ int bval[NTHR][CAPP];
    __shared__ int ovf;

    const int tid = threadIdx.x;
    const int chunk = blockIdx.x & (NCHUNK - 1);  // b*128 + n (same XCD for all q)
    const int q = blockIdx.x >> 10;               // vocab quarter
    const int b = chunk >> 7;
    const int n = chunk & 127;

    int v = 0;
    if (tid < TOKS_PER_CHUNK) {
        v = tokens[(size_t)chunk * TOKS_PER_CHUNK + tid];
        toks[tid] = v;
    }
    bcnt[tid] = 0;
    if (tid == 0) ovf = 0;
    asm volatile("s_waitcnt lgkmcnt(0)" ::: "memory");
    __builtin_amdgcn_s_barrier();

    // token outputs (overlap the LDS bucketing; only quarter-0 blocks)
    if (q == 0 && tid < TOKS_PER_CHUNK) {
        const float fv = (float)v;
        out[(size_t)b * NT_COLS + TOKS_PER_CHUNK + n * TOKS_PER_CHUNK + tid] = fv;
        if (tid < NHEAD) {
            out[(size_t)b * NT_COLS + n * NHEAD + tid] = fv;                    // new_tokens cat
            out[(size_t)NT_TOTAL + b * TOKS_PER_CHUNK + n * NHEAD + tid] = fv;  // cat_ids
        }
    }

    if (tid < TOKS_PER_CHUNK) {   // push v to its owner thread if in this quarter
        const unsigned gl = (unsigned)(v >> 2) - (unsigned)(q * QF4);
        if (gl < QF4) {
            const int o = (int)(gl & (NTHR - 1u)); // owner thread of slot gl
            unsigned slot = atomicAdd(&bcnt[o], 1u);
            if (slot < CAP) bval[o][slot] = v;
            else ovf = 1;                          // racy same-value store, read after barrier
        }
    }
    asm volatile("s_waitcnt lgkmcnt(0)" ::: "memory");
    __builtin_amdgcn_s_barrier();

    float* __restrict__ row = out + (size_t)HIST_OFF + (size_t)chunk * VOCAB;
    f32x4* __restrict__ row4 = reinterpret_cast<f32x4*>(row) + q * QF4;
    const f32x4 z = {0.f, 0.f, 0.f, 0.f};

    if (__builtin_expect(ovf, 0)) {
        // Fallback (any-data correctness): zero all, full drain, scan, scatter.
        #pragma unroll
        for (int k = 0; k < 3; ++k) row4[tid + (k << 9)] = z;
        if (tid < QTAIL) row4[3 * 512 + tid] = z;
        __syncthreads();
        if (tid < TOKS_PER_CHUNK) {
            int c = 0, first = -1;
            for (int j = 0; j < TOKS_PER_CHUNK; ++j) {
                const int u = toks[j];
                c += (u == v);
                if (u == v && first < 0) first = j;
            }
            const unsigned gl = (unsigned)(v >> 2) - (unsigned)(q * QF4);
            if (first == tid && gl < QF4) row[v] = (float)c;
        }
        return;
    }

    // ---- compose final f4 values in registers (avg 0.125 entries/thread) ----
    f32x4 f0 = z, f1 = z, f2 = z, f3 = z;
    const int n_e = (int)bcnt[tid];                // <= CAP
    for (int e = 0; e < n_e; ++e) {
        const int ve = bval[tid][e];
        int c = 0; bool first = true;
        for (int e2 = 0; e2 < n_e; ++e2) {
            const int u = bval[tid][e2];
            c += (u == ve);
            if (u == ve && e2 < e) first = false;
        }
        if (first) {
            const unsigned gl = (unsigned)(ve >> 2) - (unsigned)(q * QF4);
            const int k = (int)(gl >> 9);          // sub-slot 0..3 (512 apart)
            const int elem = ve & 3;
            const float fc = (float)c;
            #pragma unroll
            for (int j = 0; j < 4; ++j) {          // compile-time lanes only
                f0[j] = (k == 0 && j == elem) ? fc : f0[j];
                f1[j] = (k == 1 && j == elem) ? fc : f1[j];
                f2[j] = (k == 2 && j == elem) ? fc : f2[j];
                f3[j] = (k == 3 && j == elem) ? fc : f3[j];
            }
        }
    }

    // ---- burst: final values, unconditional, no drain needed afterwards ----
    row4[tid]            = f0;
    row4[512 + tid]      = f1;
    row4[1024 + tid]     = f2;
    if (tid < QTAIL) row4[1536 + tid] = f3;
}

extern "C" void kernel_launch(void* const* d_in, const int* in_sizes, int n_in,
                              void* d_out, int out_size, void* d_ws, size_t ws_size,
                              hipStream_t stream) {
    const int* tokens = (const int*)d_in[0];
    float* out = (float*)d_out;
    fused_kernel<<<NCHUNK * NSPLIT, NTHR, 0, stream>>>(tokens, out);
}

// Round 14
// 24.309 us; speedup vs baseline: 1.0236x; 1.0236x over previous
//
#include <hip/hip_runtime.h>

// Problem constants (fixed by setup_inputs): B=8, L=16384, H=2, BLOCK=128, VOCAB=32000
#define NB        8
#define LLEN      16384
#define NHEAD     2
#define BLOCKSZ   128
#define VOCAB     32000
#define NBLK      (LLEN / BLOCKSZ)                  // 128
#define NCHUNK    (NB * NBLK)                       // 1024
#define TOKS_PER_CHUNK (BLOCKSZ * NHEAD)            // 256
#define NT_COLS   (TOKS_PER_CHUNK + LLEN * NHEAD)   // 33024 per batch row
#define NT_TOTAL  (NB * NT_COLS)                    // 264192
#define CAT_TOTAL (NB * TOKS_PER_CHUNK)             // 2048
#define HIST_OFF  (NT_TOTAL + CAT_TOTAL)            // 266240
#define NF4       (VOCAB / 4)                       // 8000 f4 slots per row
#define NSPLIT    8
#define QF4       (NF4 / NSPLIT)                    // 1000 f4 slots per eighth
#define QTAIL     (QF4 - 3 * 256)                   // 232 tail f4s (threads t<232)
#define CAP       16                                // bucket capacity (overflow -> fallback)
#define CAPP      17                                // padded stride (kills LDS bank conflicts)

typedef float f32x4 __attribute__((ext_vector_type(4)));

// R12 structure (best: 24.58 µs). 8192 blocks: one per (chunk, eighth); XCD
// mapping chunk=bid&1023, q=bid>>10 keeps a chunk's 8 splits on one XCD (token
// line fetched once, L2-hit for the other 7). Bucketing runs FIRST (2 lgkm-only
// barriers, overlapped with token-output stores), each thread composes its
// final f4 values in registers, then the burst stores FINAL values — every f4
// written exactly once, no vmcnt drain, no rewrite tail; block exits as stores
// issue, freeing the CU slot for the next dispatch round (4 rounds pipeline).
__global__ __launch_bounds__(256) void fused_kernel(const int* __restrict__ tokens,
                                                    float* __restrict__ out) {
    __shared__ int toks[TOKS_PER_CHUNK];
    __shared__ unsigned bcnt[256];
    __shared__ int bval[256][CAPP];
    __shared__ int ovf;

    const int tid = threadIdx.x;
    const int chunk = blockIdx.x & (NCHUNK - 1);  // b*128 + n (same XCD for all q)
    const int q = blockIdx.x >> 10;               // vocab eighth
    const int b = chunk >> 7;
    const int n = chunk & 127;

    const int v = tokens[(size_t)chunk * TOKS_PER_CHUNK + tid];

    toks[tid] = v;
    bcnt[tid] = 0;
    if (tid == 0) ovf = 0;
    asm volatile("s_waitcnt lgkmcnt(0)" ::: "memory");
    __builtin_amdgcn_s_barrier();

    // token outputs (global stores overlap the LDS bucketing below)
    if (q == 0) {
        const float fv = (float)v;
        out[(size_t)b * NT_COLS + TOKS_PER_CHUNK + n * TOKS_PER_CHUNK + tid] = fv;
        if (tid < NHEAD) {
            out[(size_t)b * NT_COLS + n * NHEAD + tid] = fv;                    // new_tokens cat
            out[(size_t)NT_TOTAL + b * TOKS_PER_CHUNK + n * NHEAD + tid] = fv;  // cat_ids
        }
    }

    {   // push v to its owner thread if it falls in this block's eighth
        const unsigned gl = (unsigned)(v >> 2) - (unsigned)(q * QF4);
        if (gl < QF4) {
            const int o = (int)(gl & 255u);        // owner thread of slot gl
            unsigned slot = atomicAdd(&bcnt[o], 1u);
            if (slot < CAP) bval[o][slot] = v;
            else ovf = 1;                          // racy same-value store, read after barrier
        }
    }
    asm volatile("s_waitcnt lgkmcnt(0)" ::: "memory");
    __builtin_amdgcn_s_barrier();

    float* __restrict__ row = out + (size_t)HIST_OFF + (size_t)chunk * VOCAB;
    f32x4* __restrict__ row4 = reinterpret_cast<f32x4*>(row) + q * QF4;
    const f32x4 z = {0.f, 0.f, 0.f, 0.f};

    if (__builtin_expect(ovf, 0)) {
        // Fallback (any-data correctness): zero all, drain, scan, scatter.
        #pragma unroll
        for (int k = 0; k < 3; ++k) row4[tid + (k << 8)] = z;
        if (tid < QTAIL) row4[768 + tid] = z;
        __syncthreads();
        int c = 0, first = -1;
        for (int j = 0; j < TOKS_PER_CHUNK; ++j) {
            const int u = toks[j];
            c += (u == v);
            if (u == v && first < 0) first = j;
        }
        const unsigned gl = (unsigned)(v >> 2) - (unsigned)(q * QF4);
        if (first == tid && gl < QF4) row[v] = (float)c;
        return;
    }

    // ---- compose final f4 values in registers (avg 0.125 entries/thread) ----
    f32x4 f0 = z, f1 = z, f2 = z, f3 = z;
    const int n_e = (int)bcnt[tid];                // <= CAP
    for (int e = 0; e < n_e; ++e) {
        const int ve = bval[tid][e];
        int c = 0; bool first = true;
        for (int e2 = 0; e2 < n_e; ++e2) {
            const int u = bval[tid][e2];
            c += (u == ve);
            if (u == ve && e2 < e) first = false;
        }
        if (first) {
            const unsigned gl = (unsigned)(ve >> 2) - (unsigned)(q * QF4);
            const int k = (int)(gl >> 8);          // sub-slot 0..3
            const int elem = ve & 3;
            const float fc = (float)c;
            #pragma unroll
            for (int j = 0; j < 4; ++j) {          // compile-time lanes only
                f0[j] = (k == 0 && j == elem) ? fc : f0[j];
                f1[j] = (k == 1 && j == elem) ? fc : f1[j];
                f2[j] = (k == 2 && j == elem) ? fc : f2[j];
                f3[j] = (k == 3 && j == elem) ? fc : f3[j];
            }
        }
    }

    // ---- burst: final values, unconditional, no drain needed afterwards ----
    row4[tid]       = f0;
    row4[256 + tid] = f1;
    row4[512 + tid] = f2;
    if (tid < QTAIL) row4[768 + tid] = f3;
}

extern "C" void kernel_launch(void* const* d_in, const int* in_sizes, int n_in,
                              void* d_out, int out_size, void* d_ws, size_t ws_size,
                              hipStream_t stream) {
    const int* tokens = (const int*)d_in[0];
    float* out = (float*)d_out;
    fused_kernel<<<NCHUNK * NSPLIT, 256, 0, stream>>>(tokens, out);
}